// Round 9
// baseline (6015.448 us; speedup 1.0000x reference)
//
#include <hip/hip_runtime.h>
#include <cstdint>
#include <cstddef>

typedef _Float16 half8  __attribute__((ext_vector_type(8)));
typedef float    floatx4 __attribute__((ext_vector_type(4)));
typedef unsigned int uintx4 __attribute__((ext_vector_type(4)));

#define T_STEPS 1500
#define BATCH   16
#define FDIM    440
#define FPAD    448
#define HDIM    512
#define MROWS   (T_STEPS*BATCH)   /* 24000 */
#define NGATES  1024
#define EXW     4096              /* u64 words per tagged snapshot (32 KB) */
#define POLL_BUDGET 4096          /* per-wait; ~5 ms worst before sticky dead */

// ---------------- small utility kernels ----------------

__global__ __launch_bounds__(256) void cvt_pad(const float* __restrict__ src,
                                               _Float16* __restrict__ dst,
                                               int src_cols, int dst_cols) {
    int row = blockIdx.x;
    for (int k = threadIdx.x; k < dst_cols; k += 256) {
        float v = (k < src_cols) ? src[(size_t)row * src_cols + k] : 0.f;
        dst[(size_t)row * dst_cols + k] = (_Float16)v;
    }
}

__global__ __launch_bounds__(256) void cat2(const float* __restrict__ a,
                                            const float* __restrict__ b,
                                            float* __restrict__ dst) {
    int i = blockIdx.x * 256 + threadIdx.x;
    if (i < 1024) dst[i] = (i < 512) ? a[i] : b[i - 512];
}

// ---------------- GEMM: C[M,1024] = A[M,Kp] * B[1024,Kp]^T + bias (layer 0 gates) ----

__global__ __launch_bounds__(256) void gemm_tn(const _Float16* __restrict__ A,
                                               const _Float16* __restrict__ B,
                                               const float* __restrict__ bias,
                                               float* __restrict__ C32,
                                               _Float16* __restrict__ C16,
                                               int M, int Kp, int use_f32) {
    __shared__ _Float16 As[128 * 40];
    __shared__ _Float16 Bs[128 * 40];

    const int tid = threadIdx.x;
    const int wv = tid >> 6, l = tid & 63, q = l >> 4, c = l & 15;
    const int wr = wv >> 1, wc = wv & 1;
    const int m0 = blockIdx.y * 128, n0 = blockIdx.x * 128;

    floatx4 acc[4][4] = {};

    for (int kt = 0; kt < Kp; kt += 32) {
#pragma unroll
        for (int i = 0; i < 2; ++i) {
            int s = tid + i * 256;
            int row = s >> 2, qq = s & 3;
            uint4 va = {0u, 0u, 0u, 0u};
            int gm = m0 + row;
            if (gm < M) va = *(const uint4*)(A + (size_t)gm * Kp + kt + qq * 8);
            *(uint4*)(As + row * 40 + qq * 8) = va;
            uint4 vb = *(const uint4*)(B + (size_t)(n0 + row) * Kp + kt + qq * 8);
            *(uint4*)(Bs + row * 40 + qq * 8) = vb;
        }
        __syncthreads();

        half8 af[4], bf[4];
#pragma unroll
        for (int mi = 0; mi < 4; ++mi)
            af[mi] = *(const half8*)(As + (wr * 64 + mi * 16 + c) * 40 + q * 8);
#pragma unroll
        for (int ni = 0; ni < 4; ++ni)
            bf[ni] = *(const half8*)(Bs + (wc * 64 + ni * 16 + c) * 40 + q * 8);
#pragma unroll
        for (int mi = 0; mi < 4; ++mi)
#pragma unroll
            for (int ni = 0; ni < 4; ++ni)
                acc[mi][ni] = __builtin_amdgcn_mfma_f32_16x16x32_f16(af[mi], bf[ni], acc[mi][ni], 0, 0, 0);
        __syncthreads();
    }

#pragma unroll
    for (int ni = 0; ni < 4; ++ni) {
        int n = n0 + wc * 64 + ni * 16 + c;
        float bv = bias[n];
#pragma unroll
        for (int mi = 0; mi < 4; ++mi) {
#pragma unroll
            for (int r = 0; r < 4; ++r) {
                int gm = m0 + wr * 64 + mi * 16 + q * 4 + r;
                if (gm < M) {
                    float v = acc[mi][ni][r] + bv;
                    if (use_f32) C32[(size_t)gm * NGATES + n] = v;
                    else         C16[(size_t)gm * NGATES + n] = (_Float16)v;
                }
            }
        }
    }
}

// ---------------- tagged MALL exchange (sc0 sc1 = agent-coherent, r3-proven) ----------------
// u64 word = (tag32 << 32) | 2xf16: one store => tag+data atomically consistent.
// Writer: fire-and-forget sc0 sc1 store (no drain, no flag). Reader: poll own
// 64B with s_sleep backoff (poll result IS the data); per-wait budget ->
// sticky per-thread dead -> fast termination instead of hang (r6 lesson).

__device__ __forceinline__ void st64cc(unsigned long long* p, unsigned long long v) {
    asm volatile("global_store_dwordx2 %0, %1, off sc0 sc1" :: "v"(p), "v"(v) : "memory");
}

__device__ __forceinline__ void stage_tagged(const unsigned long long* __restrict__ src,
                                             unsigned tag, int j, char* lds, int& dead) {
    const unsigned long long* p = src + (size_t)j * 8;
    const int b  = j >> 5;            // batch
    const int ks = (j & 31) >> 1;     // k-slice
    const int q2 = (j & 1) * 2;       // q-chunk pair
    uintx4 A, B, C, D;
    int bud = POLL_BUDGET;
    for (;;) {
        asm volatile(
            "global_load_dwordx4 %0, %4, off sc0 sc1\n\t"
            "global_load_dwordx4 %1, %4, off offset:16 sc0 sc1\n\t"
            "global_load_dwordx4 %2, %4, off offset:32 sc0 sc1\n\t"
            "global_load_dwordx4 %3, %4, off offset:48 sc0 sc1\n\t"
            "s_waitcnt vmcnt(0)"
            : "=&v"(A), "=&v"(B), "=&v"(C), "=&v"(D) : "v"(p) : "memory");
        if (dead) break;
        unsigned bad = ((unsigned)A.y ^ tag) | ((unsigned)A.w ^ tag) |
                       ((unsigned)B.y ^ tag) | ((unsigned)B.w ^ tag) |
                       ((unsigned)C.y ^ tag) | ((unsigned)C.w ^ tag) |
                       ((unsigned)D.y ^ tag) | ((unsigned)D.w ^ tag);
        if (bad == 0u) break;
        if (--bud < 0) { dead = 1; break; }
        __builtin_amdgcn_s_sleep(4);   // ~256 cy backoff: rare polls, no MALL flood
    }
    uint32_t* l0 = (uint32_t*)(lds + ks * 1040 + (q2 * 16 + b) * 16);
    l0[0] = (uint32_t)A.x; l0[1] = (uint32_t)A.z; l0[2] = (uint32_t)B.x; l0[3] = (uint32_t)B.z;
    uint32_t* l1 = (uint32_t*)(lds + ks * 1040 + ((q2 + 1) * 16 + b) * 16);
    l1[0] = (uint32_t)C.x; l1[1] = (uint32_t)C.z; l1[2] = (uint32_t)D.x; l1[3] = (uint32_t)D.z;
}

// ---------------- fused 2-layer persistent scan, tagged MALL exchange ----------------
// 16 WGs x 512 thr. WGs 0-7: layer-0 (64 feats each); WGs 8-15: layer-1.
// Per step: poll own tagged words (backoff) -> LDS -> MFMA -> epilogue ->
// fire-and-forget tagged stores. No flags, no drains, no barrier counters.

__global__ __launch_bounds__(512, 1) void ligru_fused(
        const float* __restrict__ gates32, const _Float16* __restrict__ gates16,
        const _Float16* __restrict__ U0z, const _Float16* __restrict__ U0h,
        const _Float16* __restrict__ U1z, const _Float16* __restrict__ U1h,
        const _Float16* __restrict__ W1z, const _Float16* __restrict__ W1h,
        unsigned long long* __restrict__ exA,   // [2][EXW] layer-0 h ring
        unsigned long long* __restrict__ exC,   // [2][EXW] layer-1 h ring
        unsigned long long* __restrict__ H1T,   // [T_STEPS][EXW] tagged layer-0 out
        const float* __restrict__ bh1, const float* __restrict__ bz1,
        float* __restrict__ out, int use_gf32) {

    __shared__ char ldsX[16 * 1040];
    __shared__ char ldsY[16 * 1040];
    __shared__ float accS[2][4][16][16];

    const int tid = threadIdx.x;
    const int l = tid & 63, wv = tid >> 6, q = l >> 4, c = l & 15;
    const int gate = wv >> 2, ti = wv & 3;           // 8 waves = 2 gates x 4 tiles
    const bool isA = (blockIdx.x < 8);
    const int wg = blockIdx.x & 7;
    const int fbase = wg * 64;

    const int eb  = tid >> 5;                        // batch
    const int fpl = tid & 31;
    const int f0  = 2 * fpl;
    const int gf  = fbase + f0;                      // global feature (even)
    const int eti = f0 >> 4, efi = f0 & 15;
    const int exi = eb * 256 + (fbase >> 1) + fpl;   // this thread's u64 word

    int dead = 0;

    if (isA) {
        // ---- layer 0 ----
        const _Float16* U = (gate == 0) ? U0z : U0h;
        const int urow = fbase + ti * 16 + c;
        half8 u[16];
#pragma unroll
        for (int ks = 0; ks < 16; ++ks)
            u[ks] = *(const half8*)(U + (size_t)urow * HDIM + ks * 32 + q * 8);
#pragma unroll
        for (int ks = 0; ks < 16; ++ks)
            asm volatile("" : "+v"(u[ks]));

        float h0 = 0.f, h1 = 0.f;
        float gw0[2], gw1[2], gz0[2], gz1[2];        // 2-step gate prefetch
        auto gload = [&](int t, int s) {
            const int row = t * BATCH + eb;
            if (use_gf32) {
                float2 a2 = *(const float2*)(gates32 + (size_t)row * NGATES + gf);
                float2 b2 = *(const float2*)(gates32 + (size_t)row * NGATES + 512 + gf);
                gw0[s] = a2.x; gw1[s] = a2.y; gz0[s] = b2.x; gz1[s] = b2.y;
            } else {
                union { uint32_t u; _Float16 h[2]; } ua, ub;
                ua.u = *(const uint32_t*)(gates16 + (size_t)row * NGATES + gf);
                ub.u = *(const uint32_t*)(gates16 + (size_t)row * NGATES + 512 + gf);
                gw0[s] = (float)ua.h[0]; gw1[s] = (float)ua.h[1];
                gz0[s] = (float)ub.h[0]; gz1[s] = (float)ub.h[1];
            }
        };
        gload(0, 0);
        gload(1, 1);

        for (int t = 0; t < T_STEPS; ++t) {
            stage_tagged(exA + (size_t)(t & 1) * EXW, (unsigned)t, tid, ldsX, dead);
            __syncthreads();

            floatx4 acc = {0.f, 0.f, 0.f, 0.f};
#pragma unroll
            for (int ks = 0; ks < 16; ++ks) {
                half8 a = *(const half8*)(ldsX + ks * 1040 + l * 16);
                acc = __builtin_amdgcn_mfma_f32_16x16x32_f16(a, u[ks], acc, 0, 0, 0);
            }
            *(floatx4*)&accS[gate][ti][c][q * 4] = acc;
            __syncthreads();

            float Sz0 = accS[0][eti][efi][eb],     Sh0 = accS[1][eti][efi][eb];
            float Sz1 = accS[0][eti][efi + 1][eb], Sh1 = accS[1][eti][efi + 1][eb];

            const int s = t & 1;
            float z0 = 1.f / (1.f + __expf(-(gz0[s] + Sz0)));
            float z1 = 1.f / (1.f + __expf(-(gz1[s] + Sz1)));
            float hc0 = fmaxf(0.f, gw0[s] + Sh0);
            float hc1 = fmaxf(0.f, gw1[s] + Sh1);
            h0 = z0 * h0 + (1.f - z0) * hc0;
            h1 = z1 * h1 + (1.f - z1) * hc1;

            union { _Float16 h[2]; uint32_t u; } pk;
            pk.h[0] = (_Float16)h0; pk.h[1] = (_Float16)h1;
            unsigned long long tg = ((unsigned long long)(unsigned)(t + 1) << 32) | pk.u;
            st64cc(exA + (size_t)((t + 1) & 1) * EXW + exi, tg);   // fire-and-forget
            st64cc(H1T + (size_t)t * EXW + exi, tg);

            if (t + 2 < T_STEPS) gload(t + 2, s);
        }
    } else {
        // ---- layer 1 (input projection folded in) ----
        const _Float16* Wm = (gate == 0) ? W1z : W1h;
        const _Float16* Um = (gate == 0) ? U1z : U1h;
        const int urow = fbase + ti * 16 + c;
        half8 w[16], u[16];
#pragma unroll
        for (int ks = 0; ks < 16; ++ks) {
            w[ks] = *(const half8*)(Wm + (size_t)urow * HDIM + ks * 32 + q * 8);
            u[ks] = *(const half8*)(Um + (size_t)urow * HDIM + ks * 32 + q * 8);
        }
#pragma unroll
        for (int ks = 0; ks < 16; ++ks) {
            asm volatile("" : "+v"(w[ks]));
            asm volatile("" : "+v"(u[ks]));
        }

        const float bzv0 = bz1[gf], bzv1 = bz1[gf + 1];
        const float bhv0 = bh1[gf], bhv1 = bh1[gf + 1];
        float h0 = 0.f, h1 = 0.f;

        for (int t = 0; t < T_STEPS; ++t) {
            stage_tagged(H1T + (size_t)t * EXW, (unsigned)(t + 1), tid, ldsX, dead);
            stage_tagged(exC + (size_t)(t & 1) * EXW, (unsigned)t, tid, ldsY, dead);
            __syncthreads();

            floatx4 acc = {0.f, 0.f, 0.f, 0.f};
#pragma unroll
            for (int ks = 0; ks < 16; ++ks) {
                half8 a = *(const half8*)(ldsX + ks * 1040 + l * 16);
                acc = __builtin_amdgcn_mfma_f32_16x16x32_f16(a, w[ks], acc, 0, 0, 0);
            }
#pragma unroll
            for (int ks = 0; ks < 16; ++ks) {
                half8 a = *(const half8*)(ldsY + ks * 1040 + l * 16);
                acc = __builtin_amdgcn_mfma_f32_16x16x32_f16(a, u[ks], acc, 0, 0, 0);
            }
            *(floatx4*)&accS[gate][ti][c][q * 4] = acc;
            __syncthreads();

            float Sz0 = accS[0][eti][efi][eb],     Sh0 = accS[1][eti][efi][eb];
            float Sz1 = accS[0][eti][efi + 1][eb], Sh1 = accS[1][eti][efi + 1][eb];

            float z0 = 1.f / (1.f + __expf(-(bzv0 + Sz0)));
            float z1 = 1.f / (1.f + __expf(-(bzv1 + Sz1)));
            float hc0 = fmaxf(0.f, bhv0 + Sh0);
            float hc1 = fmaxf(0.f, bhv1 + Sh1);
            h0 = z0 * h0 + (1.f - z0) * hc0;
            h1 = z1 * h1 + (1.f - z1) * hc1;

            union { _Float16 h[2]; uint32_t u; } pk;
            pk.h[0] = (_Float16)h0; pk.h[1] = (_Float16)h1;
            unsigned long long tg = ((unsigned long long)(unsigned)(t + 1) << 32) | pk.u;
            st64cc(exC + (size_t)((t + 1) & 1) * EXW + exi, tg);

            float2 o; o.x = h0; o.y = h1;
            *(float2*)(out + (size_t)(t * BATCH + eb) * HDIM + gf) = o;
        }
    }
}

// ---------------- host ----------------

extern "C" void kernel_launch(void* const* d_in, const int* in_sizes, int n_in,
                              void* d_out, int out_size, void* d_ws, size_t ws_size,
                              hipStream_t stream) {
    const float* x   = (const float*)d_in[0];
    const float* Wh0 = (const float*)d_in[1];
    const float* bh0 = (const float*)d_in[2];
    const float* Wz0 = (const float*)d_in[3];
    const float* bz0 = (const float*)d_in[4];
    const float* Uh0 = (const float*)d_in[5];
    const float* Uz0 = (const float*)d_in[6];
    const float* Wh1 = (const float*)d_in[7];
    const float* bh1 = (const float*)d_in[8];
    const float* Wz1 = (const float*)d_in[9];
    const float* bz1 = (const float*)d_in[10];
    const float* Uh1 = (const float*)d_in[11];
    const float* Uz1 = (const float*)d_in[12];
    float* out = (float*)d_out;

    uint8_t* ws = (uint8_t*)d_ws;
    size_t off = 0;
    auto alloc = [&](size_t b) { size_t o = off; off += (b + 255) & ~(size_t)255; return o; };

    const size_t EXB  = (size_t)EXW * 8;                 // 32 KB per tagged snapshot
    const size_t H1TB = (size_t)T_STEPS * EXW * 8;       // 48 MB tagged layer-0 outputs
    size_t o_exA  = alloc(2 * EXB);
    size_t o_exC  = alloc(2 * EXB);
    size_t o_h1t  = alloc(H1TB);                         // 0xAA poison never matches tags 1..1500
    size_t o_U0z  = alloc((size_t)HDIM * HDIM * 2);
    size_t o_U0h  = alloc((size_t)HDIM * HDIM * 2);
    size_t o_U1z  = alloc((size_t)HDIM * HDIM * 2);
    size_t o_U1h  = alloc((size_t)HDIM * HDIM * 2);
    size_t o_W1z  = alloc((size_t)HDIM * HDIM * 2);
    size_t o_W1h  = alloc((size_t)HDIM * HDIM * 2);
    size_t o_Wc0  = alloc((size_t)NGATES * FPAD * 2);
    size_t o_b0   = alloc(1024 * 4);
    size_t o_xb   = alloc((size_t)MROWS * FPAD * 2);
    size_t o_g    = off;
    size_t need32 = off + (size_t)MROWS * NGATES * 4;
    int use_gf32 = (ws_size >= need32) ? 1 : 0;

    unsigned long long* exA = (unsigned long long*)(ws + o_exA);
    unsigned long long* exC = (unsigned long long*)(ws + o_exC);
    unsigned long long* H1T = (unsigned long long*)(ws + o_h1t);
    _Float16* U0Z = (_Float16*)(ws + o_U0z);
    _Float16* U0H = (_Float16*)(ws + o_U0h);
    _Float16* U1Z = (_Float16*)(ws + o_U1z);
    _Float16* U1H = (_Float16*)(ws + o_U1h);
    _Float16* W1Z = (_Float16*)(ws + o_W1z);
    _Float16* W1H = (_Float16*)(ws + o_W1h);
    _Float16* WC0 = (_Float16*)(ws + o_Wc0);
    float*    B0  = (float*)(ws + o_b0);
    _Float16* XB  = (_Float16*)(ws + o_xb);
    float*    G32 = (float*)(ws + o_g);
    _Float16* G16 = (_Float16*)(ws + o_g);

    // zero both h rings (tag 0 == initial h == 0); exA/exC contiguous
    hipMemsetAsync(ws + o_exA, 0, 4 * EXB, stream);

    // fp32 -> fp16 conversions (with K padding for layer-0 GEMM)
    cvt_pad<<<MROWS, 256, 0, stream>>>(x, XB, FDIM, FPAD);
    cvt_pad<<<512, 256, 0, stream>>>(Wh0, WC0,              FDIM, FPAD);
    cvt_pad<<<512, 256, 0, stream>>>(Wz0, WC0 + 512 * FPAD, FDIM, FPAD);
    cvt_pad<<<512, 256, 0, stream>>>(Uz0, U0Z, HDIM, HDIM);
    cvt_pad<<<512, 256, 0, stream>>>(Uh0, U0H, HDIM, HDIM);
    cvt_pad<<<512, 256, 0, stream>>>(Uz1, U1Z, HDIM, HDIM);
    cvt_pad<<<512, 256, 0, stream>>>(Uh1, U1H, HDIM, HDIM);
    cvt_pad<<<512, 256, 0, stream>>>(Wz1, W1Z, HDIM, HDIM);
    cvt_pad<<<512, 256, 0, stream>>>(Wh1, W1H, HDIM, HDIM);
    cat2<<<4, 256, 0, stream>>>(bh0, bz0, B0);

    // layer-0 gates GEMM (layer-1 projection folded into the scan)
    dim3 gg(NGATES / 128, (MROWS + 127) / 128);
    gemm_tn<<<gg, 256, 0, stream>>>(XB, WC0, B0, G32, G16, MROWS, FPAD, use_gf32);

    // fused 2-layer scan: 16 WGs, tagged MALL exchange w/ backoff polling
    ligru_fused<<<16, 512, 0, stream>>>(G32, G16, U0Z, U0H, U1Z, U1H, W1Z, W1H,
                                        exA, exC, H1T, bh1, bz1, out, use_gf32);

    (void)in_sizes; (void)n_in; (void)out_size;
}